// Round 5
// baseline (2530.091 us; speedup 1.0000x reference)
//
#include <hip/hip_runtime.h>

#define IMG   512
#define RTILE 112         // output tile per block
#define RHALO 8           // halo = steps per round (8 then 7)
#define RBUF  128         // logical buffer rows/cols = RTILE + 2*RHALO
#define RLW   132         // physical row stride in words (mult of 4)
#define PHYSR 131         // physical rows: logical -1..129
#define LDSW  (4 + PHYSR * RLW)   // +4 front pad for col -1 of phys row 0

__device__ __forceinline__ float mapf(float g) {
    float t = 3.9f * g;
    return t - t * g;          // R*g*(1-g)
}

// 6-word stencil window at physical row pointer p, owned cols [0,4):
// one aligned b128 + two scalars.
__device__ __forceinline__ void rrow(const float* __restrict__ p, float* m) {
    const float4 mid = *(const float4*)p;
    m[0] = p[-1];
    m[1] = mid.x; m[2] = mid.y; m[3] = mid.z; m[4] = mid.w;
    m[5] = p[4];
}

// One temporal round: init M=map(src), run `steps` CML steps, store grid to dst
// (clipped if do_clip). Valid output region = tile interior [8,120)^2.
__global__ __launch_bounds__(1024, 8) void cml_round(
    const float* __restrict__ src,     // g_t  (round 1: drive, since g0 = drive)
    const float* __restrict__ drv,
    const float* __restrict__ Kw,
    float* __restrict__ dst,
    int steps, int do_clip)
{
    __shared__ float lds_raw[LDSW];    // 69.2 KiB -> 2 blocks/CU
    float* __restrict__ B = lds_raw + 4;   // phys row r, col c: B[r*RLW + c]

    const int tid = threadIdx.x;
    const int bid = blockIdx.x;
    const int bc  = bid / 25;               // image*channel index
    const int tl  = bid % 25;               // 5x5 tiles of 112
    const int gy0 = (tl / 5) * RTILE - RHALO;   // logical buffer row 0 -> gy0
    const int gx0 = (tl % 5) * RTILE - RHALO;   // multiple of 4
    const float* __restrict__ simg = src + (size_t)bc * (IMG*IMG);
    const float* __restrict__ dimg = drv + (size_t)bc * (IMG*IMG);
    float*       __restrict__ oimg = dst + (size_t)bc * (IMG*IMG);

    // Folded 3x3 kernel: K' = (0.85*0.3)*K + (0.85*0.7)*delta_center
    float kk[9];
    {
        const float c2 = 0.85f * 0.3f;
        const float* kp = Kw + (bc & 3) * 9;
#pragma unroll
        for (int q = 0; q < 9; q++) kk[q] = c2 * kp[q];
        kk[4] += 0.85f * 0.7f;
    }

    const int pj = tid & 31;                // col patch: owned cols 4pj..4pj+3
    const int pi = tid >> 5;                // row band:  owned rows 4pi..4pi+3
    const int y0 = pi * 4;
    const int xc = pj * 4;

    // Boundary flags + beta*drive for owned cells (registers)
    float fx[4], fy[4], dvs[16];
#pragma unroll
    for (int k = 0; k < 4; k++)
        fx[k] = ((unsigned)(gx0 + xc + k) < IMG) ? 1.0f : 0.0f;
#pragma unroll
    for (int rr = 0; rr < 4; rr++) {
        const int gy = gy0 + y0 + rr;
        fy[rr] = ((unsigned)gy < IMG) ? 1.0f : 0.0f;
#pragma unroll
        for (int k = 0; k < 4; k++) {
            const int gx = gx0 + xc + k;
            dvs[rr*4+k] = (((unsigned)gy < IMG) && ((unsigned)gx < IMG))
                        ? 0.15f * dimg[gy*IMG + gx] : 0.0f;
        }
    }

    if (tid < 4) lds_raw[tid] = 0.0f;       // front pad (read by pj=0 band pi=0)
    // Init: B = map(src) over phys rows 0..130 (logical -1..129); pad cols -> 0.
    for (int u = tid; u < PHYSR * (RLW/4); u += 1024) {
        const int r  = u / (RLW/4);
        const int xq = (u - r * (RLW/4)) * 4;
        const int gy  = gy0 + r - 1;
        const int gxb = gx0 + xq;               // mult of 4 -> aligned float4
        float4 v = make_float4(0.f, 0.f, 0.f, 0.f);
        if (xq < RBUF && (unsigned)gy < IMG && (unsigned)gxb < IMG)
            v = *(const float4*)(simg + gy*IMG + gxb);   // gxb<=508: no row cross
        v.x = mapf(v.x); v.y = mapf(v.y); v.z = mapf(v.z); v.w = mapf(v.w);
        *(float4*)(B + r*RLW + xq) = v;
    }
    __syncthreads();

    float st[16];
#pragma unroll 1
    for (int step = 0; step < steps - 1; step++) {
        {
            float a[6], b6[6], c6[6];
            const float* p = B + y0 * RLW + xc;     // phys(y0-1) = y0
            rrow(p, a);  p += RLW;
            rrow(p, b6);
#pragma unroll
            for (int rr = 0; rr < 4; rr++) {
                p += RLW;
                rrow(p, c6);
                const float fyr = fy[rr];
#pragma unroll
                for (int k = 0; k < 4; k++) {
                    float s = dvs[rr*4+k];
                    s += kk[0]*a[k]  + kk[1]*a[k+1]  + kk[2]*a[k+2];
                    s += kk[3]*b6[k] + kk[4]*b6[k+1] + kk[5]*b6[k+2];
                    s += kk[6]*c6[k] + kk[7]*c6[k+1] + kk[8]*c6[k+2];
                    const float t = 3.9f * s;
                    st[rr*4+k] = (t - t*s) * fyr * fx[k];
                }
#pragma unroll
                for (int q = 0; q < 6; q++) { a[q] = b6[q]; b6[q] = c6[q]; }
            }
        }
        __syncthreads();   // all reads done before any write
        {
            float* w = B + (y0 + 1) * RLW + xc;     // phys(y0) = y0+1
#pragma unroll
            for (int rr = 0; rr < 4; rr++) {
                *(float4*)w = make_float4(st[rr*4+0], st[rr*4+1],
                                          st[rr*4+2], st[rr*4+3]);
                w += RLW;
            }
        }
        __syncthreads();   // writes done before next step's reads
    }

    // Final step of the round: compute grid (no map), store valid interior.
    {
        float a[6], b6[6], c6[6];
        const float* p = B + y0 * RLW + xc;
        rrow(p, a);  p += RLW;
        rrow(p, b6);
#pragma unroll
        for (int rr = 0; rr < 4; rr++) {
            p += RLW;
            rrow(p, c6);
#pragma unroll
            for (int k = 0; k < 4; k++) {
                float s = dvs[rr*4+k];
                s += kk[0]*a[k]  + kk[1]*a[k+1]  + kk[2]*a[k+2];
                s += kk[3]*b6[k] + kk[4]*b6[k+1] + kk[5]*b6[k+2];
                s += kk[6]*c6[k] + kk[7]*c6[k+1] + kk[8]*c6[k+2];
                st[rr*4+k] = s;
            }
#pragma unroll
            for (int q = 0; q < 6; q++) { a[q] = b6[q]; b6[q] = c6[q]; }
        }
    }
    // Valid region: buffer [8,120)^2 -> bands pi in [2,30), patches pj in [2,30)... 
    // owned cols 4pj..4pj+3 fully inside [8,120) iff pj in [2,29]; same for rows.
    if (pi >= 2 && pi <= 29 && pj >= 2 && pj <= 29) {
        const int gxb = gx0 + xc;               // mult of 4, >= tx >= 0
        if (gxb + 3 < IMG) {                    // skip phantom cols of edge tiles
#pragma unroll
            for (int rr = 0; rr < 4; rr++) {
                const int gy = gy0 + y0 + rr;   // >= ty >= 0
                if (gy < IMG) {
                    float4 v = make_float4(st[rr*4+0], st[rr*4+1],
                                           st[rr*4+2], st[rr*4+3]);
                    if (do_clip) {
                        v.x = fminf(fmaxf(v.x, 1e-4f), 1.0f - 1e-4f);
                        v.y = fminf(fmaxf(v.y, 1e-4f), 1.0f - 1e-4f);
                        v.z = fminf(fmaxf(v.z, 1e-4f), 1.0f - 1e-4f);
                        v.w = fminf(fmaxf(v.w, 1e-4f), 1.0f - 1e-4f);
                    }
                    *(float4*)(oimg + gy*IMG + gxb) = v;
                }
            }
        }
    }
}

// ---------------- Fallback: single-kernel 15-step version (Round-4) ----------
#define TILE  128
#define OFF_Y 16
#define OFF_X 18
#define BUFY  160
#define BUFX  164
#define LW    172
#define NP    1014

__device__ __forceinline__ void read_row6(const float* __restrict__ p, int xw,
                                          float* m) {
    const float4 mid = *(const float4*)(p + xw + 4);
    m[0] = p[xw + 3];
    m[1] = mid.x; m[2] = mid.y; m[3] = mid.z; m[4] = mid.w;
    m[5] = p[xw + 8];
}

__global__ __launch_bounds__(1024, 4) void cml_fused(
    const float* __restrict__ drive,
    const float* __restrict__ Kw,
    float* __restrict__ out)
{
    __shared__ float lds[BUFY * LW];
    const int tid = threadIdx.x;
    const int bid = blockIdx.x;
    const int bc  = bid >> 4;
    const int tl  = bid & 15;
    const int gy0 = (tl >> 2) * TILE - OFF_Y;
    const int gx0 = (tl & 3)  * TILE - OFF_X;
    const float* __restrict__ img  = drive + (size_t)bc * (IMG*IMG);
    float*       __restrict__ oimg = out   + (size_t)bc * (IMG*IMG);
    float kk[9];
    {
        const float c2 = 0.85f * 0.3f;
        const float* kp = Kw + (bc & 3) * 9;
#pragma unroll
        for (int q = 0; q < 9; q++) kk[q] = c2 * kp[q];
        kk[4] += 0.85f * 0.7f;
    }
    const int t2 = tid < NP ? tid : NP - 1;
    const int pi = t2 / 39;
    const int pj = t2 - pi * 39;
    const int y0 = 2 + 6 * pi;
    const int xw = 4 * pj;
    float dvs[24], fx[4], fy[6];
#pragma unroll
    for (int k = 0; k < 4; k++)
        fx[k] = ((unsigned)(gx0 + xw + 4 + k) < IMG) ? 1.0f : 0.0f;
#pragma unroll
    for (int rr = 0; rr < 6; rr++) {
        const int gy = gy0 + y0 + rr;
        fy[rr] = ((unsigned)gy < IMG) ? 1.0f : 0.0f;
#pragma unroll
        for (int k = 0; k < 4; k++) {
            const int gx = gx0 + xw + 4 + k;
            dvs[rr*4+k] = (((unsigned)gy < IMG) && ((unsigned)gx < IMG))
                        ? 0.15f * img[gy*IMG + gx] : 0.0f;
        }
    }
    for (int u = tid; u < BUFY * (LW/2); u += 1024) {
        const int yy = u / (LW/2);
        const int xx = (u - yy * (LW/2)) * 2;
        const int gy = gy0 + yy;
        const int gxb = gx0 + xx;
        float2 v = make_float2(0.f, 0.f);
        if (xx < BUFX && (unsigned)gy < IMG && (unsigned)gxb < IMG)
            v = *(const float2*)(img + gy*IMG + gxb);
        v.x = mapf(v.x); v.y = mapf(v.y);
        *(float2*)(lds + yy*LW + xx) = v;
    }
    __syncthreads();
    float st[24];
#pragma unroll 1
    for (int step = 0; step < 14; step++) {
        {
            float a[6], b[6], c[6];
            const float* p = lds + (y0 - 1) * LW;
            read_row6(p, xw, a);  p += LW;
            read_row6(p, xw, b);
#pragma unroll
            for (int rr = 0; rr < 6; rr++) {
                p += LW;
                read_row6(p, xw, c);
                const float fyr = fy[rr];
#pragma unroll
                for (int k = 0; k < 4; k++) {
                    float s = dvs[rr*4+k];
                    s += kk[0]*a[k] + kk[1]*a[k+1] + kk[2]*a[k+2];
                    s += kk[3]*b[k] + kk[4]*b[k+1] + kk[5]*b[k+2];
                    s += kk[6]*c[k] + kk[7]*c[k+1] + kk[8]*c[k+2];
                    const float t = 3.9f * s;
                    st[rr*4+k] = (t - t*s) * fyr * fx[k];
                }
#pragma unroll
                for (int q = 0; q < 6; q++) { a[q] = b[q]; b[q] = c[q]; }
            }
        }
        __syncthreads();
        {
            float* w = lds + y0 * LW + xw + 4;
#pragma unroll
            for (int rr = 0; rr < 6; rr++) {
                *(float4*)w = make_float4(st[rr*4+0], st[rr*4+1],
                                          st[rr*4+2], st[rr*4+3]);
                w += LW;
            }
        }
        __syncthreads();
    }
    {
        float a[6], b[6], c[6];
        const float* p = lds + (y0 - 1) * LW;
        read_row6(p, xw, a);  p += LW;
        read_row6(p, xw, b);
#pragma unroll
        for (int rr = 0; rr < 6; rr++) {
            p += LW;
            read_row6(p, xw, c);
#pragma unroll
            for (int k = 0; k < 4; k++) {
                float s = dvs[rr*4+k];
                s += kk[0]*a[k] + kk[1]*a[k+1] + kk[2]*a[k+2];
                s += kk[3]*b[k] + kk[4]*b[k+1] + kk[5]*b[k+2];
                s += kk[6]*c[k] + kk[7]*c[k+1] + kk[8]*c[k+2];
                st[rr*4+k] = fminf(fmaxf(s, 1e-4f), 1.0f - 1e-4f);
            }
#pragma unroll
            for (int q = 0; q < 6; q++) { a[q] = b[q]; b[q] = c[q]; }
        }
    }
#pragma unroll
    for (int rr = 0; rr < 6; rr++) {
        const int r = y0 + rr;
        if (r >= OFF_Y && r < OFF_Y + TILE) {
#pragma unroll
            for (int h = 0; h < 2; h++) {
                const int col = xw + 4 + 2*h;
                if (col >= OFF_X && col + 1 < OFF_X + TILE) {
                    *(float2*)(oimg + (size_t)(gy0 + r) * IMG + (gx0 + col)) =
                        make_float2(st[rr*4 + 2*h], st[rr*4 + 2*h + 1]);
                }
            }
        }
    }
}

extern "C" void kernel_launch(void* const* d_in, const int* in_sizes, int n_in,
                              void* d_out, int out_size, void* d_ws, size_t ws_size,
                              hipStream_t stream)
{
    const float* drive = (const float*)d_in[0];
    const float* Kw    = (const float*)d_in[1];
    float* out         = (float*)d_out;
    const size_t need  = (size_t)256 * IMG * IMG * sizeof(float);  // 256 MiB

    if (ws_size >= need) {
        float* g8 = (float*)d_ws;
        // Round 1: g0=drive, 8 steps -> g8 (unclipped) in ws
        cml_round<<<dim3(6400), dim3(1024), 0, stream>>>(drive, drive, Kw, g8, 8, 0);
        // Round 2: g8, 7 steps -> clipped g15 in out
        cml_round<<<dim3(6400), dim3(1024), 0, stream>>>(g8, drive, Kw, out, 7, 1);
    } else {
        cml_fused<<<dim3(4096), dim3(1024), 0, stream>>>(drive, Kw, out);
    }
}

// Round 6
// 1669.735 us; speedup vs baseline: 1.5153x; 1.5153x over previous
//
#include <hip/hip_runtime.h>

#define IMG   512
#define RTILE 112         // output tile per block
#define RHALO 8           // halo = steps per round (8 then 7)
#define RBUF  128         // logical buffer rows/cols = RTILE + 2*RHALO
#define RLW   132         // physical row stride in words (mult of 4)
#define PHYSR 131         // physical rows: logical -1..129
#define LDSW  (4 + PHYSR * RLW)   // +4 front pad for col -1 of phys row 0

__device__ __forceinline__ float mapf(float g) {
    float t = 3.9f * g;
    return t - t * g;          // R*g*(1-g)
}

// 10-word stencil window (cols xc-1 .. xc+8) at physical row pointer p:
// two aligned b128 + two scalars.
__device__ __forceinline__ void rrow10(const float* __restrict__ p, float* m) {
    const float4 lo = *(const float4*)p;
    const float4 hi = *(const float4*)(p + 4);
    m[0] = p[-1];
    m[1] = lo.x; m[2] = lo.y; m[3] = lo.z; m[4] = lo.w;
    m[5] = hi.x; m[6] = hi.y; m[7] = hi.z; m[8] = hi.w;
    m[9] = p[8];
}

// One temporal round: init M=map(src), run `steps` CML steps, store grid to dst
// (clipped if do_clip). Valid output region = tile interior [8,120)^2.
// 512 threads; each owns an 8-wide x 4-tall patch.
__global__ __launch_bounds__(512, 4) void cml_round(
    const float* __restrict__ src,     // g_t  (round 1: drive, since g0 = drive)
    const float* __restrict__ drv,
    const float* __restrict__ Kw,
    float* __restrict__ dst,
    int steps, int do_clip)
{
    __shared__ float lds_raw[LDSW];    // 69.2 KiB -> 2 blocks/CU
    float* __restrict__ B = lds_raw + 4;   // phys row r, col c: B[r*RLW + c]

    const int tid = threadIdx.x;
    const int bid = blockIdx.x;
    const int bc  = bid / 25;               // image*channel index
    const int tl  = bid % 25;               // 5x5 tiles of 112
    const int gy0 = (tl / 5) * RTILE - RHALO;   // logical buffer row 0 -> gy0
    const int gx0 = (tl % 5) * RTILE - RHALO;   // multiple of 4
    const float* __restrict__ simg = src + (size_t)bc * (IMG*IMG);
    const float* __restrict__ dimg = drv + (size_t)bc * (IMG*IMG);
    float*       __restrict__ oimg = dst + (size_t)bc * (IMG*IMG);

    // Folded 3x3 kernel: K' = (0.85*0.3)*K + (0.85*0.7)*delta_center
    float kk[9];
    {
        const float c2 = 0.85f * 0.3f;
        const float* kp = Kw + (bc & 3) * 9;
#pragma unroll
        for (int q = 0; q < 9; q++) kk[q] = c2 * kp[q];
        kk[4] += 0.85f * 0.7f;
    }

    const int pj = tid & 15;                // col patch: owned cols 8pj..8pj+7
    const int pi = tid >> 4;                // row band:  owned rows 4pi..4pi+3
    const int y0 = pi * 4;
    const int xc = pj * 8;

    // Boundary flags + beta*drive for owned cells (registers)
    float fx[8], fy[4], dvs[32];
#pragma unroll
    for (int k = 0; k < 8; k++)
        fx[k] = ((unsigned)(gx0 + xc + k) < IMG) ? 1.0f : 0.0f;
#pragma unroll
    for (int rr = 0; rr < 4; rr++) {
        const int gy = gy0 + y0 + rr;
        fy[rr] = ((unsigned)gy < IMG) ? 1.0f : 0.0f;
#pragma unroll
        for (int k = 0; k < 8; k++) {
            const int gx = gx0 + xc + k;
            dvs[rr*8+k] = (((unsigned)gy < IMG) && ((unsigned)gx < IMG))
                        ? 0.15f * dimg[gy*IMG + gx] : 0.0f;
        }
    }

    if (tid < 4) lds_raw[tid] = 0.0f;       // front pad (col -1 of phys row 0)
    // Init: B = map(src) over phys rows 0..130 (logical -1..129); pad cols -> 0.
    for (int u = tid; u < PHYSR * (RLW/4); u += 512) {
        const int r  = u / (RLW/4);
        const int xq = (u - r * (RLW/4)) * 4;
        const int gy  = gy0 + r - 1;
        const int gxb = gx0 + xq;               // mult of 4 -> aligned float4
        float4 v = make_float4(0.f, 0.f, 0.f, 0.f);
        if (xq < RBUF && (unsigned)gy < IMG && (unsigned)gxb < IMG)
            v = *(const float4*)(simg + gy*IMG + gxb);   // gxb<=508: no row cross
        v.x = mapf(v.x); v.y = mapf(v.y); v.z = mapf(v.z); v.w = mapf(v.w);
        *(float4*)(B + r*RLW + xq) = v;
    }
    __syncthreads();

    float st[32];
#pragma unroll 1
    for (int step = 0; step < steps - 1; step++) {
        {
            float a[10], b[10], c[10];
            const float* p = B + y0 * RLW + xc;     // phys(y0-1) = y0
            rrow10(p, a);  p += RLW;
            rrow10(p, b);
#pragma unroll
            for (int rr = 0; rr < 4; rr++) {
                p += RLW;
                rrow10(p, c);
                const float fyr = fy[rr];
#pragma unroll
                for (int k = 0; k < 8; k++) {
                    float s = dvs[rr*8+k];
                    s += kk[0]*a[k] + kk[1]*a[k+1] + kk[2]*a[k+2];
                    s += kk[3]*b[k] + kk[4]*b[k+1] + kk[5]*b[k+2];
                    s += kk[6]*c[k] + kk[7]*c[k+1] + kk[8]*c[k+2];
                    const float t = 3.9f * s;
                    st[rr*8+k] = (t - t*s) * fyr * fx[k];
                }
#pragma unroll
                for (int q = 0; q < 10; q++) { a[q] = b[q]; b[q] = c[q]; }
            }
        }
        __syncthreads();   // all reads done before any write (WAR)
        {
            float* w = B + (y0 + 1) * RLW + xc;     // phys(y0) = y0+1
#pragma unroll
            for (int rr = 0; rr < 4; rr++) {
                *(float4*)(w)     = make_float4(st[rr*8+0], st[rr*8+1],
                                                st[rr*8+2], st[rr*8+3]);
                *(float4*)(w + 4) = make_float4(st[rr*8+4], st[rr*8+5],
                                                st[rr*8+6], st[rr*8+7]);
                w += RLW;
            }
        }
        __syncthreads();   // writes done before next step's reads (RAW)
    }

    // Final step of the round: compute grid (no map), store valid interior.
    {
        float a[10], b[10], c[10];
        const float* p = B + y0 * RLW + xc;
        rrow10(p, a);  p += RLW;
        rrow10(p, b);
#pragma unroll
        for (int rr = 0; rr < 4; rr++) {
            p += RLW;
            rrow10(p, c);
#pragma unroll
            for (int k = 0; k < 8; k++) {
                float s = dvs[rr*8+k];
                s += kk[0]*a[k] + kk[1]*a[k+1] + kk[2]*a[k+2];
                s += kk[3]*b[k] + kk[4]*b[k+1] + kk[5]*b[k+2];
                s += kk[6]*c[k] + kk[7]*c[k+1] + kk[8]*c[k+2];
                st[rr*8+k] = s;
            }
#pragma unroll
            for (int q = 0; q < 10; q++) { a[q] = b[q]; b[q] = c[q]; }
        }
    }
    // Valid region: buffer [8,120)^2 -> pj in [1,14], pi in [2,29].
    if (pi >= 2 && pi <= 29 && pj >= 1 && pj <= 14) {
        const int gxb = gx0 + xc;               // mult of 4, >= tile origin >= 0
#pragma unroll
        for (int rr = 0; rr < 4; rr++) {
            const int gy = gy0 + y0 + rr;       // >= 0 always (pi>=2)
            if (gy < IMG) {
#pragma unroll
                for (int h = 0; h < 2; h++) {
                    if (gxb + 4*h + 3 < IMG) {
                        float4 v = make_float4(st[rr*8+4*h+0], st[rr*8+4*h+1],
                                               st[rr*8+4*h+2], st[rr*8+4*h+3]);
                        if (do_clip) {
                            v.x = fminf(fmaxf(v.x, 1e-4f), 1.0f - 1e-4f);
                            v.y = fminf(fmaxf(v.y, 1e-4f), 1.0f - 1e-4f);
                            v.z = fminf(fmaxf(v.z, 1e-4f), 1.0f - 1e-4f);
                            v.w = fminf(fmaxf(v.w, 1e-4f), 1.0f - 1e-4f);
                        }
                        *(float4*)(oimg + gy*IMG + gxb + 4*h) = v;
                    }
                }
            }
        }
    }
}

// ---------------- Fallback: single-kernel 15-step version (Round-4) ----------
#define TILE  128
#define OFF_Y 16
#define OFF_X 18
#define BUFY  160
#define BUFX  164
#define LW    172
#define NP    1014

__device__ __forceinline__ void read_row6(const float* __restrict__ p, int xw,
                                          float* m) {
    const float4 mid = *(const float4*)(p + xw + 4);
    m[0] = p[xw + 3];
    m[1] = mid.x; m[2] = mid.y; m[3] = mid.z; m[4] = mid.w;
    m[5] = p[xw + 8];
}

__global__ __launch_bounds__(1024, 4) void cml_fused(
    const float* __restrict__ drive,
    const float* __restrict__ Kw,
    float* __restrict__ out)
{
    __shared__ float lds[BUFY * LW];
    const int tid = threadIdx.x;
    const int bid = blockIdx.x;
    const int bc  = bid >> 4;
    const int tl  = bid & 15;
    const int gy0 = (tl >> 2) * TILE - OFF_Y;
    const int gx0 = (tl & 3)  * TILE - OFF_X;
    const float* __restrict__ img  = drive + (size_t)bc * (IMG*IMG);
    float*       __restrict__ oimg = out   + (size_t)bc * (IMG*IMG);
    float kk[9];
    {
        const float c2 = 0.85f * 0.3f;
        const float* kp = Kw + (bc & 3) * 9;
#pragma unroll
        for (int q = 0; q < 9; q++) kk[q] = c2 * kp[q];
        kk[4] += 0.85f * 0.7f;
    }
    const int t2 = tid < NP ? tid : NP - 1;
    const int pi = t2 / 39;
    const int pj = t2 - pi * 39;
    const int y0 = 2 + 6 * pi;
    const int xw = 4 * pj;
    float dvs[24], fx[4], fy[6];
#pragma unroll
    for (int k = 0; k < 4; k++)
        fx[k] = ((unsigned)(gx0 + xw + 4 + k) < IMG) ? 1.0f : 0.0f;
#pragma unroll
    for (int rr = 0; rr < 6; rr++) {
        const int gy = gy0 + y0 + rr;
        fy[rr] = ((unsigned)gy < IMG) ? 1.0f : 0.0f;
#pragma unroll
        for (int k = 0; k < 4; k++) {
            const int gx = gx0 + xw + 4 + k;
            dvs[rr*4+k] = (((unsigned)gy < IMG) && ((unsigned)gx < IMG))
                        ? 0.15f * img[gy*IMG + gx] : 0.0f;
        }
    }
    for (int u = tid; u < BUFY * (LW/2); u += 1024) {
        const int yy = u / (LW/2);
        const int xx = (u - yy * (LW/2)) * 2;
        const int gy = gy0 + yy;
        const int gxb = gx0 + xx;
        float2 v = make_float2(0.f, 0.f);
        if (xx < BUFX && (unsigned)gy < IMG && (unsigned)gxb < IMG)
            v = *(const float2*)(img + gy*IMG + gxb);
        v.x = mapf(v.x); v.y = mapf(v.y);
        *(float2*)(lds + yy*LW + xx) = v;
    }
    __syncthreads();
    float st[24];
#pragma unroll 1
    for (int step = 0; step < 14; step++) {
        {
            float a[6], b[6], c[6];
            const float* p = lds + (y0 - 1) * LW;
            read_row6(p, xw, a);  p += LW;
            read_row6(p, xw, b);
#pragma unroll
            for (int rr = 0; rr < 6; rr++) {
                p += LW;
                read_row6(p, xw, c);
                const float fyr = fy[rr];
#pragma unroll
                for (int k = 0; k < 4; k++) {
                    float s = dvs[rr*4+k];
                    s += kk[0]*a[k] + kk[1]*a[k+1] + kk[2]*a[k+2];
                    s += kk[3]*b[k] + kk[4]*b[k+1] + kk[5]*b[k+2];
                    s += kk[6]*c[k] + kk[7]*c[k+1] + kk[8]*c[k+2];
                    const float t = 3.9f * s;
                    st[rr*4+k] = (t - t*s) * fyr * fx[k];
                }
#pragma unroll
                for (int q = 0; q < 6; q++) { a[q] = b[q]; b[q] = c[q]; }
            }
        }
        __syncthreads();
        {
            float* w = lds + y0 * LW + xw + 4;
#pragma unroll
            for (int rr = 0; rr < 6; rr++) {
                *(float4*)w = make_float4(st[rr*4+0], st[rr*4+1],
                                          st[rr*4+2], st[rr*4+3]);
                w += LW;
            }
        }
        __syncthreads();
    }
    {
        float a[6], b[6], c[6];
        const float* p = lds + (y0 - 1) * LW;
        read_row6(p, xw, a);  p += LW;
        read_row6(p, xw, b);
#pragma unroll
        for (int rr = 0; rr < 6; rr++) {
            p += LW;
            read_row6(p, xw, c);
#pragma unroll
            for (int k = 0; k < 4; k++) {
                float s = dvs[rr*4+k];
                s += kk[0]*a[k] + kk[1]*a[k+1] + kk[2]*a[k+2];
                s += kk[3]*b[k] + kk[4]*b[k+1] + kk[5]*b[k+2];
                s += kk[6]*c[k] + kk[7]*c[k+1] + kk[8]*c[k+2];
                st[rr*4+k] = fminf(fmaxf(s, 1e-4f), 1.0f - 1e-4f);
            }
#pragma unroll
            for (int q = 0; q < 6; q++) { a[q] = b[q]; b[q] = c[q]; }
        }
    }
#pragma unroll
    for (int rr = 0; rr < 6; rr++) {
        const int r = y0 + rr;
        if (r >= OFF_Y && r < OFF_Y + TILE) {
#pragma unroll
            for (int h = 0; h < 2; h++) {
                const int col = xw + 4 + 2*h;
                if (col >= OFF_X && col + 1 < OFF_X + TILE) {
                    *(float2*)(oimg + (size_t)(gy0 + r) * IMG + (gx0 + col)) =
                        make_float2(st[rr*4 + 2*h], st[rr*4 + 2*h + 1]);
                }
            }
        }
    }
}

extern "C" void kernel_launch(void* const* d_in, const int* in_sizes, int n_in,
                              void* d_out, int out_size, void* d_ws, size_t ws_size,
                              hipStream_t stream)
{
    const float* drive = (const float*)d_in[0];
    const float* Kw    = (const float*)d_in[1];
    float* out         = (float*)d_out;
    const size_t need  = (size_t)256 * IMG * IMG * sizeof(float);  // 256 MiB

    if (ws_size >= need) {
        float* g8 = (float*)d_ws;
        // Round 1: g0=drive, 8 steps -> g8 (unclipped) in ws
        cml_round<<<dim3(6400), dim3(512), 0, stream>>>(drive, drive, Kw, g8, 8, 0);
        // Round 2: g8, 7 steps -> clipped g15 in out
        cml_round<<<dim3(6400), dim3(512), 0, stream>>>(g8, drive, Kw, out, 7, 1);
    } else {
        cml_fused<<<dim3(4096), dim3(1024), 0, stream>>>(drive, Kw, out);
    }
}

// Round 7
// 1348.975 us; speedup vs baseline: 1.8756x; 1.2378x over previous
//
#include <hip/hip_runtime.h>

#define IMG   512
#define RTILE 112         // output tile per block
#define RHALO 8           // halo = steps per round (8 then 7)
#define RBUF  128         // logical buffer rows/cols = RTILE + 2*RHALO
#define RLW   132         // physical row stride in words (mult of 4)
#define PHYSR 131         // physical rows: logical -1..129
#define LDSW  (4 + PHYSR * RLW)   // +4 front pad for col -1 of phys row 0

__device__ __forceinline__ float mapf(float g) {
    float t = 3.9f * g;
    return t - t * g;          // R*g*(1-g)
}

// 6-word stencil window (cols xc-1 .. xc+4) at physical row pointer p:
// one aligned b128 + two scalars (merge to ds_read2_b32).
__device__ __forceinline__ void rrow6(const float* __restrict__ p, float* m) {
    const float4 mid = *(const float4*)p;
    m[0] = p[-1];
    m[1] = mid.x; m[2] = mid.y; m[3] = mid.z; m[4] = mid.w;
    m[5] = p[4];
}

// One temporal round: init M=map(src), run `steps` CML steps, store grid to dst
// (clipped if do_clip). Valid output region = tile interior [8,120)^2.
// 512 threads; each owns a 4-wide x 8-tall patch.
// waves_per_eu(4,4): LDS already caps us at 2 blocks/CU = 4 waves/EU; pinning
// min=max=4 unlocks the 128-VGPR budget (otherwise the allocator targets 8
// waves/EU at 64 VGPRs and spills ~100 floats/thread -> 600 MB scratch traffic).
__global__ __launch_bounds__(512) __attribute__((amdgpu_waves_per_eu(4, 4)))
void cml_round(
    const float* __restrict__ src,     // g_t  (round 1: drive, since g0 = drive)
    const float* __restrict__ drv,
    const float* __restrict__ Kw,
    float* __restrict__ dst,
    int steps, int do_clip)
{
    __shared__ float lds_raw[LDSW];    // 69.2 KiB -> 2 blocks/CU
    float* __restrict__ B = lds_raw + 4;   // phys row r, col c: B[r*RLW + c]

    const int tid = threadIdx.x;
    const int bid = blockIdx.x;
    const int bc  = bid / 25;               // image*channel index
    const int tl  = bid % 25;               // 5x5 tiles of 112
    const int gy0 = (tl / 5) * RTILE - RHALO;   // logical buffer row 0 -> gy0
    const int gx0 = (tl % 5) * RTILE - RHALO;   // multiple of 4
    const float* __restrict__ simg = src + (size_t)bc * (IMG*IMG);
    const float* __restrict__ dimg = drv + (size_t)bc * (IMG*IMG);
    float*       __restrict__ oimg = dst + (size_t)bc * (IMG*IMG);

    // Folded 3x3 kernel: K' = (0.85*0.3)*K + (0.85*0.7)*delta_center
    float kk[9];
    {
        const float c2 = 0.85f * 0.3f;
        const float* kp = Kw + (bc & 3) * 9;
#pragma unroll
        for (int q = 0; q < 9; q++) kk[q] = c2 * kp[q];
        kk[4] += 0.85f * 0.7f;
    }

    const int pj = tid & 31;                // col patch: owned cols 4pj..4pj+3
    const int pi = tid >> 5;                // row band:  owned rows 8pi..8pi+7
    const int y0 = pi * 8;
    const int xc = pj * 4;

    // Boundary flags + beta*drive for owned cells (registers)
    float fx[4], fy[8], dvs[32];
#pragma unroll
    for (int k = 0; k < 4; k++)
        fx[k] = ((unsigned)(gx0 + xc + k) < IMG) ? 1.0f : 0.0f;
#pragma unroll
    for (int rr = 0; rr < 8; rr++) {
        const int gy = gy0 + y0 + rr;
        fy[rr] = ((unsigned)gy < IMG) ? 1.0f : 0.0f;
#pragma unroll
        for (int k = 0; k < 4; k++) {
            const int gx = gx0 + xc + k;
            dvs[rr*4+k] = (((unsigned)gy < IMG) && ((unsigned)gx < IMG))
                        ? 0.15f * dimg[gy*IMG + gx] : 0.0f;
        }
    }

    if (tid < 4) lds_raw[tid] = 0.0f;       // front pad (col -1 of phys row 0)
    // Init: B = map(src) over phys rows 0..130 (logical -1..129); pad cols -> 0.
    for (int u = tid; u < PHYSR * (RLW/4); u += 512) {
        const int r  = u / (RLW/4);
        const int xq = (u - r * (RLW/4)) * 4;
        const int gy  = gy0 + r - 1;
        const int gxb = gx0 + xq;               // mult of 4 -> aligned float4
        float4 v = make_float4(0.f, 0.f, 0.f, 0.f);
        if (xq < RBUF && (unsigned)gy < IMG && (unsigned)gxb < IMG)
            v = *(const float4*)(simg + gy*IMG + gxb);   // gxb<=508: no row cross
        v.x = mapf(v.x); v.y = mapf(v.y); v.z = mapf(v.z); v.w = mapf(v.w);
        *(float4*)(B + r*RLW + xq) = v;
    }
    __syncthreads();

    float st[32];
#pragma unroll 1
    for (int step = 0; step < steps - 1; step++) {
        {
            float a[6], b[6], c[6];
            const float* p = B + y0 * RLW + xc;     // phys y0 = logical y0-1
            rrow6(p, a);  p += RLW;
            rrow6(p, b);
#pragma unroll
            for (int rr = 0; rr < 8; rr++) {
                p += RLW;
                rrow6(p, c);
                const float fyr = fy[rr];
#pragma unroll
                for (int k = 0; k < 4; k++) {
                    float s = dvs[rr*4+k];
                    s += kk[0]*a[k] + kk[1]*a[k+1] + kk[2]*a[k+2];
                    s += kk[3]*b[k] + kk[4]*b[k+1] + kk[5]*b[k+2];
                    s += kk[6]*c[k] + kk[7]*c[k+1] + kk[8]*c[k+2];
                    const float t = 3.9f * s;
                    st[rr*4+k] = (t - t*s) * fyr * fx[k];
                }
#pragma unroll
                for (int q = 0; q < 6; q++) { a[q] = b[q]; b[q] = c[q]; }
            }
        }
        __syncthreads();   // all reads done before any write (WAR)
        {
            float* w = B + (y0 + 1) * RLW + xc;     // phys y0+1 = logical y0
#pragma unroll
            for (int rr = 0; rr < 8; rr++) {
                *(float4*)w = make_float4(st[rr*4+0], st[rr*4+1],
                                          st[rr*4+2], st[rr*4+3]);
                w += RLW;
            }
        }
        __syncthreads();   // writes done before next step's reads (RAW)
    }

    // Final step of the round: compute grid (no map), store valid interior.
    {
        float a[6], b[6], c[6];
        const float* p = B + y0 * RLW + xc;
        rrow6(p, a);  p += RLW;
        rrow6(p, b);
#pragma unroll
        for (int rr = 0; rr < 8; rr++) {
            p += RLW;
            rrow6(p, c);
#pragma unroll
            for (int k = 0; k < 4; k++) {
                float s = dvs[rr*4+k];
                s += kk[0]*a[k] + kk[1]*a[k+1] + kk[2]*a[k+2];
                s += kk[3]*b[k] + kk[4]*b[k+1] + kk[5]*b[k+2];
                s += kk[6]*c[k] + kk[7]*c[k+1] + kk[8]*c[k+2];
                st[rr*4+k] = s;
            }
#pragma unroll
            for (int q = 0; q < 6; q++) { a[q] = b[q]; b[q] = c[q]; }
        }
    }
    // Valid region: buffer [8,120)^2 -> pj in [2,29], pi in [1,14].
    if (pi >= 1 && pi <= 14 && pj >= 2 && pj <= 29) {
        const int gxb = gx0 + xc;               // mult of 4; >= 0 since pj>=2
        if (gxb + 3 < IMG) {                    // skip phantom cols of edge tiles
#pragma unroll
            for (int rr = 0; rr < 8; rr++) {
                const int gy = gy0 + y0 + rr;   // >= 0 always (pi>=1)
                if (gy < IMG) {
                    float4 v = make_float4(st[rr*4+0], st[rr*4+1],
                                           st[rr*4+2], st[rr*4+3]);
                    if (do_clip) {
                        v.x = fminf(fmaxf(v.x, 1e-4f), 1.0f - 1e-4f);
                        v.y = fminf(fmaxf(v.y, 1e-4f), 1.0f - 1e-4f);
                        v.z = fminf(fmaxf(v.z, 1e-4f), 1.0f - 1e-4f);
                        v.w = fminf(fmaxf(v.w, 1e-4f), 1.0f - 1e-4f);
                    }
                    *(float4*)(oimg + gy*IMG + gxb) = v;
                }
            }
        }
    }
}

// ---------------- Fallback: single-kernel 15-step version (Round-4) ----------
#define TILE  128
#define OFF_Y 16
#define OFF_X 18
#define BUFY  160
#define BUFX  164
#define LW    172
#define NP    1014

__device__ __forceinline__ void read_row6(const float* __restrict__ p, int xw,
                                          float* m) {
    const float4 mid = *(const float4*)(p + xw + 4);
    m[0] = p[xw + 3];
    m[1] = mid.x; m[2] = mid.y; m[3] = mid.z; m[4] = mid.w;
    m[5] = p[xw + 8];
}

__global__ __launch_bounds__(1024, 4) void cml_fused(
    const float* __restrict__ drive,
    const float* __restrict__ Kw,
    float* __restrict__ out)
{
    __shared__ float lds[BUFY * LW];
    const int tid = threadIdx.x;
    const int bid = blockIdx.x;
    const int bc  = bid >> 4;
    const int tl  = bid & 15;
    const int gy0 = (tl >> 2) * TILE - OFF_Y;
    const int gx0 = (tl & 3)  * TILE - OFF_X;
    const float* __restrict__ img  = drive + (size_t)bc * (IMG*IMG);
    float*       __restrict__ oimg = out   + (size_t)bc * (IMG*IMG);
    float kk[9];
    {
        const float c2 = 0.85f * 0.3f;
        const float* kp = Kw + (bc & 3) * 9;
#pragma unroll
        for (int q = 0; q < 9; q++) kk[q] = c2 * kp[q];
        kk[4] += 0.85f * 0.7f;
    }
    const int t2 = tid < NP ? tid : NP - 1;
    const int pi = t2 / 39;
    const int pj = t2 - pi * 39;
    const int y0 = 2 + 6 * pi;
    const int xw = 4 * pj;
    float dvs[24], fx[4], fy[6];
#pragma unroll
    for (int k = 0; k < 4; k++)
        fx[k] = ((unsigned)(gx0 + xw + 4 + k) < IMG) ? 1.0f : 0.0f;
#pragma unroll
    for (int rr = 0; rr < 6; rr++) {
        const int gy = gy0 + y0 + rr;
        fy[rr] = ((unsigned)gy < IMG) ? 1.0f : 0.0f;
#pragma unroll
        for (int k = 0; k < 4; k++) {
            const int gx = gx0 + xw + 4 + k;
            dvs[rr*4+k] = (((unsigned)gy < IMG) && ((unsigned)gx < IMG))
                        ? 0.15f * img[gy*IMG + gx] : 0.0f;
        }
    }
    for (int u = tid; u < BUFY * (LW/2); u += 1024) {
        const int yy = u / (LW/2);
        const int xx = (u - yy * (LW/2)) * 2;
        const int gy = gy0 + yy;
        const int gxb = gx0 + xx;
        float2 v = make_float2(0.f, 0.f);
        if (xx < BUFX && (unsigned)gy < IMG && (unsigned)gxb < IMG)
            v = *(const float2*)(img + gy*IMG + gxb);
        v.x = mapf(v.x); v.y = mapf(v.y);
        *(float2*)(lds + yy*LW + xx) = v;
    }
    __syncthreads();
    float st[24];
#pragma unroll 1
    for (int step = 0; step < 14; step++) {
        {
            float a[6], b[6], c[6];
            const float* p = lds + (y0 - 1) * LW;
            read_row6(p, xw, a);  p += LW;
            read_row6(p, xw, b);
#pragma unroll
            for (int rr = 0; rr < 6; rr++) {
                p += LW;
                read_row6(p, xw, c);
                const float fyr = fy[rr];
#pragma unroll
                for (int k = 0; k < 4; k++) {
                    float s = dvs[rr*4+k];
                    s += kk[0]*a[k] + kk[1]*a[k+1] + kk[2]*a[k+2];
                    s += kk[3]*b[k] + kk[4]*b[k+1] + kk[5]*b[k+2];
                    s += kk[6]*c[k] + kk[7]*c[k+1] + kk[8]*c[k+2];
                    const float t = 3.9f * s;
                    st[rr*4+k] = (t - t*s) * fyr * fx[k];
                }
#pragma unroll
                for (int q = 0; q < 6; q++) { a[q] = b[q]; b[q] = c[q]; }
            }
        }
        __syncthreads();
        {
            float* w = lds + y0 * LW + xw + 4;
#pragma unroll
            for (int rr = 0; rr < 6; rr++) {
                *(float4*)w = make_float4(st[rr*4+0], st[rr*4+1],
                                          st[rr*4+2], st[rr*4+3]);
                w += LW;
            }
        }
        __syncthreads();
    }
    {
        float a[6], b[6], c[6];
        const float* p = lds + (y0 - 1) * LW;
        read_row6(p, xw, a);  p += LW;
        read_row6(p, xw, b);
#pragma unroll
        for (int rr = 0; rr < 6; rr++) {
            p += LW;
            read_row6(p, xw, c);
#pragma unroll
            for (int k = 0; k < 4; k++) {
                float s = dvs[rr*4+k];
                s += kk[0]*a[k] + kk[1]*a[k+1] + kk[2]*a[k+2];
                s += kk[3]*b[k] + kk[4]*b[k+1] + kk[5]*b[k+2];
                s += kk[6]*c[k] + kk[7]*c[k+1] + kk[8]*c[k+2];
                st[rr*4+k] = fminf(fmaxf(s, 1e-4f), 1.0f - 1e-4f);
            }
#pragma unroll
            for (int q = 0; q < 6; q++) { a[q] = b[q]; b[q] = c[q]; }
        }
    }
#pragma unroll
    for (int rr = 0; rr < 6; rr++) {
        const int r = y0 + rr;
        if (r >= OFF_Y && r < OFF_Y + TILE) {
#pragma unroll
            for (int h = 0; h < 2; h++) {
                const int col = xw + 4 + 2*h;
                if (col >= OFF_X && col + 1 < OFF_X + TILE) {
                    *(float2*)(oimg + (size_t)(gy0 + r) * IMG + (gx0 + col)) =
                        make_float2(st[rr*4 + 2*h], st[rr*4 + 2*h + 1]);
                }
            }
        }
    }
}

extern "C" void kernel_launch(void* const* d_in, const int* in_sizes, int n_in,
                              void* d_out, int out_size, void* d_ws, size_t ws_size,
                              hipStream_t stream)
{
    const float* drive = (const float*)d_in[0];
    const float* Kw    = (const float*)d_in[1];
    float* out         = (float*)d_out;
    const size_t need  = (size_t)256 * IMG * IMG * sizeof(float);  // 256 MiB

    if (ws_size >= need) {
        float* g8 = (float*)d_ws;
        // Round 1: g0=drive, 8 steps -> g8 (unclipped) in ws
        cml_round<<<dim3(6400), dim3(512), 0, stream>>>(drive, drive, Kw, g8, 8, 0);
        // Round 2: g8, 7 steps -> clipped g15 in out
        cml_round<<<dim3(6400), dim3(512), 0, stream>>>(g8, drive, Kw, out, 7, 1);
    } else {
        cml_fused<<<dim3(4096), dim3(1024), 0, stream>>>(drive, Kw, out);
    }
}